// Round 9
// baseline (15977.800 us; speedup 1.0000x reference)
//
#include <hip/hip_runtime.h>
#include <math.h>

typedef unsigned int uint_t;
typedef unsigned short ushort_t;
typedef __bf16 bf16x8 __attribute__((ext_vector_type(8)));
typedef float f32x4 __attribute__((ext_vector_type(4)));

#define BB 512
#define TT 256
#define DD 32
#define LL 64
#define CC 128
#define HH 512
#define HE 256
#define LOG2PI_ 1.8378770664093453f
#define GK 4097
#define GSCALE 32.0f
#define GZMIN (-64.0f)

__device__ __forceinline__ float softplus_f(float x) {
  float ax = fabsf(x);
  return fmaxf(x, 0.0f) + __logf(1.0f + __expf(-ax));
}
__device__ __forceinline__ float sigmoid_f(float x) {
  return 1.0f / (1.0f + __expf(-x));
}
__device__ __forceinline__ float bf2f(ushort_t s) {
  return __uint_as_float(((uint_t)s) << 16);
}
__device__ __forceinline__ float bflo(uint_t u) { return __uint_as_float(u << 16); }
__device__ __forceinline__ float bfhi(uint_t u) { return __uint_as_float(u & 0xffff0000u); }
__device__ __forceinline__ ushort_t f2bf(float f) {
  uint_t u = __float_as_uint(f);
  return (ushort_t)((u + 0x7fffu + ((u >> 16) & 1u)) >> 16);
}

#define MFMA_B16(a,b,c) __builtin_amdgcn_mfma_f32_16x16x32_bf16(a,b,c,0,0,0)

// ---------------- prep: pack weights into MFMA fragment order -------------
__global__ void prep_kernel(
    const float* __restrict__ fW1, const float* __restrict__ hW1,
    const float* __restrict__ fW2, const float* __restrict__ hW2,
    const float* __restrict__ fW3, const float* __restrict__ hW3,
    const float* __restrict__ Wx,  const float* __restrict__ Wh,
    const float* __restrict__ encW, const float* __restrict__ projW,
    ushort_t* __restrict__ W1fp, ushort_t* __restrict__ W1hp,
    ushort_t* __restrict__ W2fp, ushort_t* __restrict__ W2hp,
    ushort_t* __restrict__ W3fp, ushort_t* __restrict__ W3hp,
    ushort_t* __restrict__ encWb,
    uint_t* __restrict__ Wgru, ushort_t* __restrict__ Wgn,
    ushort_t* __restrict__ projWp)
{
  int idx = blockIdx.x*256 + threadIdx.x;
  if (idx < 98304) {                       // W1fp: 6 ks x 32 nt
    int f = idx >> 9, e = idx & 511;
    int ks = f >> 5, nt = f & 31, l = e >> 3, j = e & 7;
    int k = ks*32 + ((l>>4)<<3) + j, n = nt*16 + (l & 15);
    W1fp[idx] = f2bf(fW1[k*512 + n]);
  } else if (idx < 131072) {               // W1hp: 2 ks x 32 nt
    int r = idx - 98304;
    int f = r >> 9, e = r & 511;
    int ks = f >> 5, nt = f & 31, l = e >> 3, j = e & 7;
    int k = ks*32 + ((l>>4)<<3) + j, n = nt*16 + (l & 15);
    W1hp[r] = f2bf(hW1[k*512 + n]);
  } else if (idx < 393216) {               // W2fp: 16 ks x 32 nt
    int r = idx - 131072;
    int f = r >> 9, e = r & 511;
    int ks = f >> 5, nt = f & 31, l = e >> 3, j = e & 7;
    int k = ks*32 + ((l>>4)<<3) + j, n = nt*16 + (l & 15);
    W2fp[r] = f2bf(fW2[k*512 + n]);
  } else if (idx < 655360) {               // W2hp
    int r = idx - 393216;
    int f = r >> 9, e = r & 511;
    int ks = f >> 5, nt = f & 31, l = e >> 3, j = e & 7;
    int k = ks*32 + ((l>>4)<<3) + j, n = nt*16 + (l & 15);
    W2hp[r] = f2bf(hW2[k*512 + n]);
  } else if (idx < 688128) {               // W3fp: 16 ks x 4 nt
    int r = idx - 655360;
    int f = r >> 9, e = r & 511;
    int ks = f >> 2, nt = f & 3, l = e >> 3, j = e & 7;
    int k = ks*32 + ((l>>4)<<3) + j, n = nt*16 + (l & 15);
    W3fp[r] = f2bf(fW3[k*64 + n]);
  } else if (idx < 720896) {               // W3hp
    int r = idx - 688128;
    int f = r >> 9, e = r & 511;
    int ks = f >> 2, nt = f & 3, l = e >> 3, j = e & 7;
    int k = ks*32 + ((l>>4)<<3) + j, n = nt*16 + (l & 15);
    W3hp[r] = f2bf(hW3[k*64 + n]);
  } else if (idx < 753664) {               // encWb
    int r = idx - 720896;
    encWb[r] = f2bf(encW[r]);
  } else if (idx < 827648) {               // GRU weights: (k<289, j<256)
    int r = idx - 753664;
    int k = r >> 8, j = r & 255;
    float wr, wu, wn;
    if (k < 33) { wr = Wx[k*768 + j]; wu = Wx[k*768 + 256 + j]; wn = Wx[k*768 + 512 + j]; }
    else { int kk = k - 33; wr = Wh[kk*768 + j]; wu = Wh[kk*768 + 256 + j]; wn = Wh[kk*768 + 512 + j]; }
    Wgru[r] = (uint_t)f2bf(wr) | ((uint_t)f2bf(wu) << 16);
    Wgn[r]  = f2bf(wn);
  } else if (idx < 829696) {               // projWp: 2 ks x 2 nt
    int r = idx - 827648;
    int f = r >> 9, e = r & 511;
    int ks = f >> 1, nt = f & 1, l = e >> 3, j = e & 7;
    int k = ks*32 + ((l>>4)<<3) + j, n = nt*16 + (l & 15);
    projWp[r] = f2bf(projW[k*32 + n]);
  }
}

// ---------------- g-function lookup table -----------------------------------
__global__ void lut_kernel(const float* __restrict__ gw1, const float* __restrict__ gb1,
                           const float* __restrict__ gw2, const float* __restrict__ gb2,
                           float* __restrict__ gtab)
{
  int idx = blockIdx.x*256 + threadIdx.x;
  if (idx >= 64*GK) return;
  int l = idx / GK, i = idx - l*GK;
  float z = GZMIN + (float)i*(1.0f/GSCALE);
  float s = 0.f;
  for (int h = 0; h < 512; ++h)
    s += softplus_f(z*gw1[l*512+h] + gb1[l*512+h]) * gw2[l*512+h];
  gtab[idx] = sigmoid_f(s + gb2[l]);
}

// ---------------- GRU scan + enc projection (round-5, passing) ---------------
__global__ __launch_bounds__(512) void gru_kernel(
    const float* __restrict__ xs, const float* __restrict__ ts,
    const uint_t* __restrict__ Wgru, const ushort_t* __restrict__ Wgn,
    const float* __restrict__ gb,
    const ushort_t* __restrict__ encWb, const float* __restrict__ encb,
    float* __restrict__ ctx)
{
  __shared__ __align__(16) float hstate[HE][2];
  __shared__ __align__(16) float xv[33][2];
  __shared__ __align__(16) float par[2][HE][2][4];
  __shared__ __align__(16) float encp[2][2][CC];
  const int tid = threadIdx.x;
  const int b0 = blockIdx.x*2;
  const int j = tid & 255;
  const int kh = tid >> 8;
  for (int i = tid; i < HE*2; i += 512) ((float*)hstate)[i] = 0.f;
  __syncthreads();
  for (int t = 0; t < TT; ++t) {
    if (tid < 66) {
      int k = tid >> 1, r = tid & 1;
      xv[k][r] = (k < 32) ? xs[((size_t)(b0+r)*TT + t)*DD + k] : ts[t];
    }
    __syncthreads();
    {
      float pr0=0,pr1=0,pu0=0,pu1=0,px0=0,px1=0,ph0=0,ph1=0;
      if (kh == 0) {
        #pragma unroll 3
        for (int k = 0; k < 33; ++k) {
          uint_t ru = Wgru[k*256 + j];
          float wr = bflo(ru), wu = bfhi(ru), wn = bf2f(Wgn[k*256 + j]);
          float2 a = *(const float2*)&xv[k][0];
          pr0 += a.x*wr; pr1 += a.y*wr;
          pu0 += a.x*wu; pu1 += a.y*wu;
          px0 += a.x*wn; px1 += a.y*wn;
        }
        #pragma unroll 8
        for (int k = 33; k < 145; ++k) {
          uint_t ru = Wgru[k*256 + j];
          float wr = bflo(ru), wu = bfhi(ru), wn = bf2f(Wgn[k*256 + j]);
          float2 a = *(const float2*)&hstate[k-33][0];
          pr0 += a.x*wr; pr1 += a.y*wr;
          pu0 += a.x*wu; pu1 += a.y*wu;
          ph0 += a.x*wn; ph1 += a.y*wn;
        }
      } else {
        #pragma unroll 8
        for (int k = 145; k < 289; ++k) {
          uint_t ru = Wgru[k*256 + j];
          float wr = bflo(ru), wu = bfhi(ru), wn = bf2f(Wgn[k*256 + j]);
          float2 a = *(const float2*)&hstate[k-33][0];
          pr0 += a.x*wr; pr1 += a.y*wr;
          pu0 += a.x*wu; pu1 += a.y*wu;
          ph0 += a.x*wn; ph1 += a.y*wn;
        }
      }
      *(float4*)&par[kh][j][0][0] = make_float4(pr0,pu0,px0,ph0);
      *(float4*)&par[kh][j][1][0] = make_float4(pr1,pu1,px1,ph1);
    }
    __syncthreads();
    if (tid < 256) {
      float br = gb[j], bu = gb[256+j], bn = gb[512+j];
      #pragma unroll
      for (int r = 0; r < 2; ++r) {
        float4 p0 = *(const float4*)&par[0][j][r][0];
        float4 p1 = *(const float4*)&par[1][j][r][0];
        float rg = sigmoid_f(p0.x+p1.x+br);
        float ug = sigmoid_f(p0.y+p1.y+bu);
        float ng = tanhf(p0.z+p1.z+bn + rg*(p0.w+p1.w));
        hstate[j][r] = (1.f-ug)*ng + ug*hstate[j][r];
      }
    }
    __syncthreads();
    {
      int c = tid & 127, rr = (tid>>7)&1, k0 = (tid>>8)*128;
      float acc = 0.f;
      #pragma unroll 8
      for (int k = k0; k < k0+128; ++k)
        acc += hstate[k][rr]*bf2f(encWb[k*CC + c]);
      encp[tid>>8][rr][c] = acc;
    }
    __syncthreads();
    if (tid < 256) {
      int c = tid & 127, rr = tid>>7;
      ctx[((size_t)t*BB + b0 + rr)*CC + c] = encp[0][rr][c] + encp[1][rr][c] + encb[c];
    }
  }
}

// ---------------- fused SDE scan: MFMA + depth-8 register queue --------------
// 32 blocks x 512 threads (8 waves). Block owns 16 batch rows.
#define AP_SCAT(row,k) (((k)>>5)*512 + ((row) + ((((k)>>3)&3)<<4))*8 + ((k)&7))

// LDS layout (bytes):
#define O_INP  0         // 6144:  bf16 frag-packed z(ks0-1)||ctx(ks2-5)
#define O_A1F  6144      // 16384
#define O_A1H  22528     // 16384
#define O_A2F  38912     // 16384
#define O_A2H  55296     // 16384
#define O_L3F  71680     // 4096:  f32 [16][64] fz
#define O_L3H  75776     // 4096:  f32 [16][64] hz
#define SMEM_SZ 79872

// Single-stream, wave covers 4 nt, depth-8 rotating b-frag queue.
// Register budget: b[8]=32 VGPR, acc[4]=16, a0/a1=8.
template<int KS>
__device__ __forceinline__ void phaseN4(
    const ushort_t* __restrict__ W, int nt0, const __bf16* A, int lane, f32x4* acc)
{
  constexpr int NF = KS*4;
  constexpr int D = 8;
  const size_t lo = (size_t)lane*8;
  bf16x8 b[D];
  #pragma unroll
  for (int d = 0; d < D; ++d) {
    int ks = d >> 2, i = d & 3;
    b[d] = *(const bf16x8*)(W + ((size_t)(ks*32 + nt0 + i) << 9) + lo);
  }
  bf16x8 a0 = *(const bf16x8*)(A + lo);
  bf16x8 a1 = a0;
  #pragma unroll
  for (int f = 0; f < NF; ++f) {
    const int ks = f >> 2, i = f & 3;
    if (i == 0 && ks + 1 < KS)
      a1 = *(const bf16x8*)(A + ((size_t)(ks+1) << 9) + lo);
    acc[i] = MFMA_B16(a0, b[f % D], acc[i]);
    if (f + D < NF) {
      const int f2 = f + D, ks2 = f2 >> 2, i2 = f2 & 3;
      b[f % D] = *(const bf16x8*)(W + ((size_t)(ks2*32 + nt0 + i2) << 9) + lo);
    }
    if (i == 3) a0 = a1;
  }
}

// Single nt per wave (layer3), depth-8 queue.
template<int KS, int NTS>
__device__ __forceinline__ void phaseN1(
    const ushort_t* __restrict__ W, int nt, const __bf16* A, int lane, f32x4& acc)
{
  constexpr int D = 8;
  const size_t lo = (size_t)lane*8;
  bf16x8 b[D];
  #pragma unroll
  for (int d = 0; d < D; ++d)
    b[d] = *(const bf16x8*)(W + ((size_t)(d*NTS + nt) << 9) + lo);
  bf16x8 a0 = *(const bf16x8*)(A + lo);
  bf16x8 a1 = a0;
  #pragma unroll
  for (int ks = 0; ks < KS; ++ks) {
    if (ks + 1 < KS)
      a1 = *(const bf16x8*)(A + ((size_t)(ks+1) << 9) + lo);
    acc = MFMA_B16(a0, b[ks % D], acc);
    if (ks + D < KS)
      b[ks % D] = *(const bf16x8*)(W + ((size_t)((ks+D)*NTS + nt) << 9) + lo);
    a0 = a1;
  }
}

#define WRITE_ACT(dst, acc, biasp) { \
  _Pragma("unroll") \
  for (int i = 0; i < 4; ++i) { \
    int c = ((w*4 + i)<<4) + (lane & 15); \
    float bv = (biasp)[c]; \
    _Pragma("unroll") \
    for (int j = 0; j < 4; ++j) \
      dst[AP_SCAT(((lane>>4)<<2) + j, c)] = (__bf16)softplus_f((acc)[i][j] + bv); \
  } }

__global__ __attribute__((amdgpu_waves_per_eu(2, 2))) __launch_bounds__(512)
void sde_kernel(
  const float* __restrict__ ctx, const float* __restrict__ ts,
  const float* __restrict__ eps0, const float* __restrict__ dW,
  const float* __restrict__ qzW, const float* __restrict__ qzb,
  const float* __restrict__ pm, const float* __restrict__ pls,
  const ushort_t* __restrict__ W1fp, const ushort_t* __restrict__ W1hp,
  const ushort_t* __restrict__ W2fp, const ushort_t* __restrict__ W2hp,
  const ushort_t* __restrict__ W3fp, const ushort_t* __restrict__ W3hp,
  const float* __restrict__ fb1, const float* __restrict__ hb1,
  const float* __restrict__ fb2, const float* __restrict__ hb2,
  const float* __restrict__ fb3, const float* __restrict__ hb3,
  const float* __restrict__ gtab,
  const float* __restrict__ gw1, const float* __restrict__ gb1,
  const float* __restrict__ gw2, const float* __restrict__ gb2,
  const ushort_t* __restrict__ projWp, const float* __restrict__ projb,
  float* __restrict__ out)
{
  __shared__ __align__(16) unsigned char smem[SMEM_SZ];
  __bf16* INp = (__bf16*)(smem + O_INP);
  __bf16* A1f = (__bf16*)(smem + O_A1F);
  __bf16* A1h = (__bf16*)(smem + O_A1H);
  __bf16* A2f = (__bf16*)(smem + O_A2F);
  __bf16* A2h = (__bf16*)(smem + O_A2H);
  float*  l3f = (float*)(smem + O_L3F);
  float*  l3h = (float*)(smem + O_L3H);

  const int tid = threadIdx.x;
  const int b0 = blockIdx.x * 16;
  const int w = tid >> 6, lane = tid & 63;

  // per-thread persistent state: rows w and w+8, column l=lane
  float zA, zB, dlA = 0.f, dlB = 0.f, lqA, lqB, dwA, dwB;

  // ---- z0 phase ----
  {
    float* ctx0f = (float*)A1f;   // scratch
    float* qf    = (float*)A1h;   // scratch
    #pragma unroll
    for (int q = 0; q < 4; ++q) {
      int o = tid + q*512;
      ctx0f[o] = ctx[(size_t)(b0 + (o>>7))*CC + (o&127)];
    }
    __syncthreads();
    #pragma unroll
    for (int q = 0; q < 4; ++q) {
      int o = tid + q*512;
      int r = o >> 7, n = o & 127;
      float acc = qzb[n];
      #pragma unroll 4
      for (int k = 0; k < CC; ++k) acc += ctx0f[r*128 + k]*qzW[k*128 + n];
      qf[o] = acc;
    }
    __syncthreads();
    #pragma unroll
    for (int e = 0; e < 2; ++e) {
      int r = w + e*8, l = lane;
      float qm  = qf[r*128 + l];
      float qls = fminf(fmaxf(qf[r*128 + 64 + l], -20.f), 2.f);
      float z0  = qm + __expf(qls)*eps0[(size_t)(b0+r)*LL + l];
      if (e == 0) zA = z0; else zB = z0;
      INp[AP_SCAT(r, l)] = (__bf16)z0;
      float dp = (z0 - pm[l])*__expf(-pls[l]);
      float dq = (z0 - qm)*__expf(-qls);
      float v = (-0.5f*dp*dp - pls[l]) - (-0.5f*dq*dq - qls);
      #pragma unroll
      for (int off = 1; off < 64; off <<= 1) v += __shfl_xor(v, off);
      if (e == 0) lqA = v; else lqB = v;
    }
    // stage ctx[1] into INp ctx region
    #pragma unroll
    for (int q = 0; q < 4; ++q) {
      int o = tid + q*512;
      int r = o >> 7, c = o & 127;
      INp[AP_SCAT(r, 64 + c)] = (__bf16)ctx[((size_t)1*BB + b0 + r)*CC + c];
    }
    dwA = dW[((size_t)0*BB + b0 + w)*LL + lane];
    dwB = dW[((size_t)0*BB + b0 + w + 8)*LL + lane];
    __syncthreads();
    if (w < 2) {
      f32x4 pc = {0,0,0,0};
      bf16x8 a0 = *(const bf16x8*)(INp + lane*8);
      bf16x8 b0f = *(const bf16x8*)(projWp + (size_t)(0*2 + w)*512 + lane*8);
      pc = MFMA_B16(a0, b0f, pc);
      bf16x8 a1 = *(const bf16x8*)(INp + 512 + lane*8);
      bf16x8 b1f = *(const bf16x8*)(projWp + (size_t)(1*2 + w)*512 + lane*8);
      pc = MFMA_B16(a1, b1f, pc);
      int col = w*16 + (lane & 15);
      float pb = projb[col];
      #pragma unroll
      for (int j = 0; j < 4; ++j) {
        int row = ((lane>>4)<<2) + j;
        out[((size_t)(b0+row)*TT + 0)*DD + col] = pc[j] + pb;
      }
    }
    __syncthreads();
  }

  // ---- SDE scan ----
  for (int t = 0; t < TT-1; ++t) {
    // P1: layer1 f (K=192, 24 frags) then h (K=64, 8 frags), depth-8 queues
    {
      f32x4 accf[4] = {{0,0,0,0},{0,0,0,0},{0,0,0,0},{0,0,0,0}};
      phaseN4<6>(W1fp, w*4, INp, lane, accf);
      WRITE_ACT(A1f, accf, fb1)
      f32x4 acch[4] = {{0,0,0,0},{0,0,0,0},{0,0,0,0},{0,0,0,0}};
      phaseN4<2>(W1hp, w*4, INp, lane, acch);
      WRITE_ACT(A1h, acch, hb1)
    }
    __syncthreads();                                   // bar1
    // P2f: layer2 f-path (A1f -> A2f), 64 frags depth-8
    {
      f32x4 acc[4] = {{0,0,0,0},{0,0,0,0},{0,0,0,0},{0,0,0,0}};
      phaseN4<16>(W2fp, w*4, A1f, lane, acc);
      WRITE_ACT(A2f, acc, fb2)
    }
    __syncthreads();                                   // bar2
    // P2h: layer2 h-path (A1h -> A2h)
    {
      f32x4 acc[4] = {{0,0,0,0},{0,0,0,0},{0,0,0,0},{0,0,0,0}};
      phaseN4<16>(W2hp, w*4, A1h, lane, acc);
      WRITE_ACT(A2h, acc, hb2)
    }
    __syncthreads();                                   // bar3
    // P3: layer3 — waves 0-3 f (nt=w), waves 4-7 h (nt=w-4), in parallel
    {
      f32x4 acc = {0,0,0,0};
      if (w < 4) phaseN1<16,4>(W3fp, w, A2f, lane, acc);
      else       phaseN1<16,4>(W3hp, w-4, A2h, lane, acc);
      int nt = (w < 4) ? w : w - 4;
      int cl = (nt<<4) + (lane & 15);
      float bv = (w < 4) ? fb3[cl] : hb3[cl];
      float* dst = (w < 4) ? l3f : l3h;
      #pragma unroll
      for (int j = 0; j < 4; ++j)
        dst[(((lane>>4)<<2) + j)*64 + cl] = acc[j] + bv;
    }
    __syncthreads();                                   // bar4

    // ---- epilogue: g via LUT, u, dlog, z update; stage ctx[t+2]/dW ----
    {
      float t0 = ts[t], t1 = ts[t+1];
      float dt = t1 - t0;
      float sqdt = sqrtf(dt);
      float sqA, sqB;
      #pragma unroll
      for (int e = 0; e < 2; ++e) {
        int r = w + e*8, l = lane;
        float zv = e ? zB : zA;
        float gz;
        if (__builtin_expect(fabsf(zv) < 63.9f, 1)) {
          float x = (zv - GZMIN)*GSCALE;
          int jx = (int)x;
          float fr = x - (float)jx;
          const float* gt = &gtab[l*GK + jx];
          float g0v = gt[0], g1v = gt[1];
          gz = g0v + (g1v - g0v)*fr;
        } else {
          float s = 0.f;
          for (int h = 0; h < 512; ++h)
            s += softplus_f(zv*gw1[l*512+h] + gb1[l*512+h]) * gw2[l*512+h];
          gz = sigmoid_f(s + gb2[l]);
        }
        float fzv = l3f[r*64 + l], hzv = l3h[r*64 + l];
        float u = (fzv - hzv)/gz;
        float sq = u*u;
        #pragma unroll
        for (int off = 1; off < 64; off <<= 1) sq += __shfl_xor(sq, off);
        float zn = zv + fzv*dt + gz*sqdt*(e ? dwB : dwA);
        if (e == 0) { sqA = sq; zA = zn; } else { sqB = sq; zB = zn; }
        INp[AP_SCAT(r, l)] = (__bf16)zn;
      }
      dlA += 0.5f*sqA*dt;
      dlB += 0.5f*sqB*dt;
      if (t + 2 < TT) {
        #pragma unroll
        for (int q = 0; q < 4; ++q) {
          int o = tid + q*512;
          int r = o >> 7, c = o & 127;
          INp[AP_SCAT(r, 64 + c)] = (__bf16)ctx[((size_t)(t+2)*BB + b0 + r)*CC + c];
        }
      }
      if (t + 1 < TT-1) {
        dwA = dW[((size_t)(t+1)*BB + b0 + w)*LL + lane];
        dwB = dW[((size_t)(t+1)*BB + b0 + w + 8)*LL + lane];
      }
    }
    __syncthreads();                                   // bar5

    // ---- proj of z_{t+1} via MFMA (waves 0,1); others proceed to next P1 ----
    if (w < 2) {
      f32x4 pc = {0,0,0,0};
      bf16x8 a0 = *(const bf16x8*)(INp + lane*8);
      bf16x8 b0f = *(const bf16x8*)(projWp + (size_t)(0*2 + w)*512 + lane*8);
      pc = MFMA_B16(a0, b0f, pc);
      bf16x8 a1 = *(const bf16x8*)(INp + 512 + lane*8);
      bf16x8 b1f = *(const bf16x8*)(projWp + (size_t)(1*2 + w)*512 + lane*8);
      pc = MFMA_B16(a1, b1f, pc);
      int col = w*16 + (lane & 15);
      float pb = projb[col];
      #pragma unroll
      for (int j = 0; j < 4; ++j) {
        int row = ((lane>>4)<<2) + j;
        out[((size_t)(b0+row)*TT + (t+1))*DD + col] = pc[j] + pb;
      }
    }
  }

  if (lane == 0) {
    out[(size_t)BB*TT*DD + b0 + w]     = lqA - dlA;
    out[(size_t)BB*TT*DD + b0 + w + 8] = lqB - dlB;
  }
}

extern "C" void kernel_launch(void* const* d_in, const int* in_sizes, int n_in,
                              void* d_out, int out_size, void* d_ws, size_t ws_size,
                              hipStream_t stream)
{
  const float* xs   = (const float*)d_in[0];
  const float* ts   = (const float*)d_in[1];
  const float* eps0 = (const float*)d_in[2];
  const float* dW   = (const float*)d_in[3];
  const float* gruWx= (const float*)d_in[4];
  const float* gruWh= (const float*)d_in[5];
  const float* grub = (const float*)d_in[6];
  const float* encW = (const float*)d_in[7];
  const float* encb = (const float*)d_in[8];
  const float* qzW  = (const float*)d_in[9];
  const float* qzb  = (const float*)d_in[10];
  const float* fW1  = (const float*)d_in[11];
  const float* fb1  = (const float*)d_in[12];
  const float* fW2  = (const float*)d_in[13];
  const float* fb2  = (const float*)d_in[14];
  const float* fW3  = (const float*)d_in[15];
  const float* fb3  = (const float*)d_in[16];
  const float* hW1  = (const float*)d_in[17];
  const float* hb1  = (const float*)d_in[18];
  const float* hW2  = (const float*)d_in[19];
  const float* hb2  = (const float*)d_in[20];
  const float* hW3  = (const float*)d_in[21];
  const float* hb3  = (const float*)d_in[22];
  const float* gw1  = (const float*)d_in[23];
  const float* gb1  = (const float*)d_in[24];
  const float* gw2  = (const float*)d_in[25];
  const float* gb2  = (const float*)d_in[26];
  const float* projW= (const float*)d_in[27];
  const float* projb= (const float*)d_in[28];
  const float* pm   = (const float*)d_in[29];
  const float* pls  = (const float*)d_in[30];
  float* out = (float*)d_out;
  float* ws  = (float*)d_ws;

  float* ctx  = ws;                              // 16,777,216 f32
  float* gtab = ctx + (size_t)16777216;          // 262,208 f32
  ushort_t* W1fp  = (ushort_t*)(gtab + 262208);  // 98,304
  ushort_t* W1hp  = W1fp + 98304;                // 32,768
  ushort_t* W2fp  = W1hp + 32768;                // 262,144
  ushort_t* W2hp  = W2fp + 262144;               // 262,144
  ushort_t* W3fp  = W2hp + 262144;               // 32,768
  ushort_t* W3hp  = W3fp + 32768;                // 32,768
  ushort_t* encWb = W3hp + 32768;                // 32,768
  uint_t*   Wgru  = (uint_t*)(encWb + 32768);    // 73,984 uints
  ushort_t* Wgn   = (ushort_t*)(Wgru + 73984);   // 73,984
  ushort_t* projWp= Wgn + 73984;                 // 2,048

  hipLaunchKernelGGL(prep_kernel, dim3(3241), dim3(256), 0, stream,
                     fW1, hW1, fW2, hW2, fW3, hW3, gruWx, gruWh, encW, projW,
                     W1fp, W1hp, W2fp, W2hp, W3fp, W3hp, encWb, Wgru, Wgn, projWp);
  hipLaunchKernelGGL(lut_kernel, dim3(1025), dim3(256), 0, stream,
                     gw1, gb1, gw2, gb2, gtab);
  hipLaunchKernelGGL(gru_kernel, dim3(256), dim3(512), 0, stream,
                     xs, ts, Wgru, Wgn, grub, encWb, encb, ctx);
  hipLaunchKernelGGL(sde_kernel, dim3(32), dim3(512), 0, stream,
                     ctx, ts, eps0, dW, qzW, qzb, pm, pls,
                     W1fp, W1hp, W2fp, W2hp, W3fp, W3hp,
                     fb1, hb1, fb2, hb2, fb3, hb3,
                     gtab, gw1, gb1, gw2, gb2, projWp, projb, out);
}

// Round 10
// 11646.161 us; speedup vs baseline: 1.3719x; 1.3719x over previous
//
#include <hip/hip_runtime.h>
#include <math.h>

typedef unsigned int uint_t;
typedef unsigned short ushort_t;
typedef __bf16 bf16x8 __attribute__((ext_vector_type(8)));
typedef float f32x4 __attribute__((ext_vector_type(4)));

#define BB 512
#define TT 256
#define DD 32
#define LL 64
#define CC 128
#define HH 512
#define HE 256
#define LOG2PI_ 1.8378770664093453f
#define GK 4097
#define GSCALE 32.0f
#define GZMIN (-64.0f)

__device__ __forceinline__ float softplus_f(float x) {
  float ax = fabsf(x);
  return fmaxf(x, 0.0f) + __logf(1.0f + __expf(-ax));
}
__device__ __forceinline__ float sigmoid_f(float x) {
  return 1.0f / (1.0f + __expf(-x));
}
__device__ __forceinline__ float bf2f(ushort_t s) {
  return __uint_as_float(((uint_t)s) << 16);
}
__device__ __forceinline__ float bflo(uint_t u) { return __uint_as_float(u << 16); }
__device__ __forceinline__ float bfhi(uint_t u) { return __uint_as_float(u & 0xffff0000u); }
__device__ __forceinline__ ushort_t f2bf(float f) {
  uint_t u = __float_as_uint(f);
  return (ushort_t)((u + 0x7fffu + ((u >> 16) & 1u)) >> 16);
}

#define MFMA_B16(a,b,c) __builtin_amdgcn_mfma_f32_16x16x32_bf16(a,b,c,0,0,0)

// async global->LDS, 16B per lane; LDS base must be wave-uniform.
__device__ __forceinline__ void gld16(const ushort_t* g, ushort_t* l) {
  __builtin_amdgcn_global_load_lds(
      (const __attribute__((address_space(1))) unsigned int*)(const void*)g,
      (__attribute__((address_space(3))) unsigned int*)(void*)l, 16, 0, 0);
}

// compile-time-folded counted vmcnt wait
__device__ __forceinline__ void waitv(int n) {
  switch (n) {
  case 0: asm volatile("s_waitcnt vmcnt(0)" ::: "memory"); break;
  case 1: asm volatile("s_waitcnt vmcnt(1)" ::: "memory"); break;
  case 2: asm volatile("s_waitcnt vmcnt(2)" ::: "memory"); break;
  case 3: asm volatile("s_waitcnt vmcnt(3)" ::: "memory"); break;
  case 4: asm volatile("s_waitcnt vmcnt(4)" ::: "memory"); break;
  case 5: asm volatile("s_waitcnt vmcnt(5)" ::: "memory"); break;
  case 6: asm volatile("s_waitcnt vmcnt(6)" ::: "memory"); break;
  default: asm volatile("s_waitcnt vmcnt(7)" ::: "memory"); break;
  }
}

// ---------------- prep: pack weights into MFMA fragment order -------------
// B-frag (ks,nt): element = W[k = ks*32 + (l>>4)*8 + j][n = nt*16 + (l&15)]
// at frag*512 + l*8 + j  -> one wave reads/stages a frag as one dwordx4/lane.
__global__ void prep_kernel(
    const float* __restrict__ fW1, const float* __restrict__ hW1,
    const float* __restrict__ fW2, const float* __restrict__ hW2,
    const float* __restrict__ fW3, const float* __restrict__ hW3,
    const float* __restrict__ Wx,  const float* __restrict__ Wh,
    const float* __restrict__ encW, const float* __restrict__ projW,
    ushort_t* __restrict__ W1fp, ushort_t* __restrict__ W1hp,
    ushort_t* __restrict__ W2fp, ushort_t* __restrict__ W2hp,
    ushort_t* __restrict__ W3fp, ushort_t* __restrict__ W3hp,
    ushort_t* __restrict__ encWb,
    uint_t* __restrict__ Wgru, ushort_t* __restrict__ Wgn,
    ushort_t* __restrict__ projWp)
{
  int idx = blockIdx.x*256 + threadIdx.x;
  if (idx < 98304) {                       // W1fp: 6 ks x 32 nt
    int f = idx >> 9, e = idx & 511;
    int ks = f >> 5, nt = f & 31, l = e >> 3, j = e & 7;
    int k = ks*32 + ((l>>4)<<3) + j, n = nt*16 + (l & 15);
    W1fp[idx] = f2bf(fW1[k*512 + n]);
  } else if (idx < 131072) {               // W1hp: 2 ks x 32 nt
    int r = idx - 98304;
    int f = r >> 9, e = r & 511;
    int ks = f >> 5, nt = f & 31, l = e >> 3, j = e & 7;
    int k = ks*32 + ((l>>4)<<3) + j, n = nt*16 + (l & 15);
    W1hp[r] = f2bf(hW1[k*512 + n]);
  } else if (idx < 393216) {               // W2fp: 16 ks x 32 nt
    int r = idx - 131072;
    int f = r >> 9, e = r & 511;
    int ks = f >> 5, nt = f & 31, l = e >> 3, j = e & 7;
    int k = ks*32 + ((l>>4)<<3) + j, n = nt*16 + (l & 15);
    W2fp[r] = f2bf(fW2[k*512 + n]);
  } else if (idx < 655360) {               // W2hp
    int r = idx - 393216;
    int f = r >> 9, e = r & 511;
    int ks = f >> 5, nt = f & 31, l = e >> 3, j = e & 7;
    int k = ks*32 + ((l>>4)<<3) + j, n = nt*16 + (l & 15);
    W2hp[r] = f2bf(hW2[k*512 + n]);
  } else if (idx < 688128) {               // W3fp: 16 ks x 4 nt
    int r = idx - 655360;
    int f = r >> 9, e = r & 511;
    int ks = f >> 2, nt = f & 3, l = e >> 3, j = e & 7;
    int k = ks*32 + ((l>>4)<<3) + j, n = nt*16 + (l & 15);
    W3fp[r] = f2bf(fW3[k*64 + n]);
  } else if (idx < 720896) {               // W3hp
    int r = idx - 688128;
    int f = r >> 9, e = r & 511;
    int ks = f >> 2, nt = f & 3, l = e >> 3, j = e & 7;
    int k = ks*32 + ((l>>4)<<3) + j, n = nt*16 + (l & 15);
    W3hp[r] = f2bf(hW3[k*64 + n]);
  } else if (idx < 753664) {               // encWb
    int r = idx - 720896;
    encWb[r] = f2bf(encW[r]);
  } else if (idx < 827648) {               // GRU weights: (k<289, j<256)
    int r = idx - 753664;
    int k = r >> 8, j = r & 255;
    float wr, wu, wn;
    if (k < 33) { wr = Wx[k*768 + j]; wu = Wx[k*768 + 256 + j]; wn = Wx[k*768 + 512 + j]; }
    else { int kk = k - 33; wr = Wh[kk*768 + j]; wu = Wh[kk*768 + 256 + j]; wn = Wh[kk*768 + 512 + j]; }
    Wgru[r] = (uint_t)f2bf(wr) | ((uint_t)f2bf(wu) << 16);
    Wgn[r]  = f2bf(wn);
  } else if (idx < 829696) {               // projWp: 2 ks x 2 nt
    int r = idx - 827648;
    int f = r >> 9, e = r & 511;
    int ks = f >> 1, nt = f & 1, l = e >> 3, j = e & 7;
    int k = ks*32 + ((l>>4)<<3) + j, n = nt*16 + (l & 15);
    projWp[r] = f2bf(projW[k*32 + n]);
  }
}

// ---------------- g-function lookup table -----------------------------------
__global__ void lut_kernel(const float* __restrict__ gw1, const float* __restrict__ gb1,
                           const float* __restrict__ gw2, const float* __restrict__ gb2,
                           float* __restrict__ gtab)
{
  int idx = blockIdx.x*256 + threadIdx.x;
  if (idx >= 64*GK) return;
  int l = idx / GK, i = idx - l*GK;
  float z = GZMIN + (float)i*(1.0f/GSCALE);
  float s = 0.f;
  for (int h = 0; h < 512; ++h)
    s += softplus_f(z*gw1[l*512+h] + gb1[l*512+h]) * gw2[l*512+h];
  gtab[idx] = sigmoid_f(s + gb2[l]);
}

// ---------------- GRU scan + enc projection (round-5, passing) ---------------
__global__ __launch_bounds__(512) void gru_kernel(
    const float* __restrict__ xs, const float* __restrict__ ts,
    const uint_t* __restrict__ Wgru, const ushort_t* __restrict__ Wgn,
    const float* __restrict__ gb,
    const ushort_t* __restrict__ encWb, const float* __restrict__ encb,
    float* __restrict__ ctx)
{
  __shared__ __align__(16) float hstate[HE][2];
  __shared__ __align__(16) float xv[33][2];
  __shared__ __align__(16) float par[2][HE][2][4];
  __shared__ __align__(16) float encp[2][2][CC];
  const int tid = threadIdx.x;
  const int b0 = blockIdx.x*2;
  const int j = tid & 255;
  const int kh = tid >> 8;
  for (int i = tid; i < HE*2; i += 512) ((float*)hstate)[i] = 0.f;
  __syncthreads();
  for (int t = 0; t < TT; ++t) {
    if (tid < 66) {
      int k = tid >> 1, r = tid & 1;
      xv[k][r] = (k < 32) ? xs[((size_t)(b0+r)*TT + t)*DD + k] : ts[t];
    }
    __syncthreads();
    {
      float pr0=0,pr1=0,pu0=0,pu1=0,px0=0,px1=0,ph0=0,ph1=0;
      if (kh == 0) {
        #pragma unroll 3
        for (int k = 0; k < 33; ++k) {
          uint_t ru = Wgru[k*256 + j];
          float wr = bflo(ru), wu = bfhi(ru), wn = bf2f(Wgn[k*256 + j]);
          float2 a = *(const float2*)&xv[k][0];
          pr0 += a.x*wr; pr1 += a.y*wr;
          pu0 += a.x*wu; pu1 += a.y*wu;
          px0 += a.x*wn; px1 += a.y*wn;
        }
        #pragma unroll 8
        for (int k = 33; k < 145; ++k) {
          uint_t ru = Wgru[k*256 + j];
          float wr = bflo(ru), wu = bfhi(ru), wn = bf2f(Wgn[k*256 + j]);
          float2 a = *(const float2*)&hstate[k-33][0];
          pr0 += a.x*wr; pr1 += a.y*wr;
          pu0 += a.x*wu; pu1 += a.y*wu;
          ph0 += a.x*wn; ph1 += a.y*wn;
        }
      } else {
        #pragma unroll 8
        for (int k = 145; k < 289; ++k) {
          uint_t ru = Wgru[k*256 + j];
          float wr = bflo(ru), wu = bfhi(ru), wn = bf2f(Wgn[k*256 + j]);
          float2 a = *(const float2*)&hstate[k-33][0];
          pr0 += a.x*wr; pr1 += a.y*wr;
          pu0 += a.x*wu; pu1 += a.y*wu;
          ph0 += a.x*wn; ph1 += a.y*wn;
        }
      }
      *(float4*)&par[kh][j][0][0] = make_float4(pr0,pu0,px0,ph0);
      *(float4*)&par[kh][j][1][0] = make_float4(pr1,pu1,px1,ph1);
    }
    __syncthreads();
    if (tid < 256) {
      float br = gb[j], bu = gb[256+j], bn = gb[512+j];
      #pragma unroll
      for (int r = 0; r < 2; ++r) {
        float4 p0 = *(const float4*)&par[0][j][r][0];
        float4 p1 = *(const float4*)&par[1][j][r][0];
        float rg = sigmoid_f(p0.x+p1.x+br);
        float ug = sigmoid_f(p0.y+p1.y+bu);
        float ng = tanhf(p0.z+p1.z+bn + rg*(p0.w+p1.w));
        hstate[j][r] = (1.f-ug)*ng + ug*hstate[j][r];
      }
    }
    __syncthreads();
    {
      int c = tid & 127, rr = (tid>>7)&1, k0 = (tid>>8)*128;
      float acc = 0.f;
      #pragma unroll 8
      for (int k = k0; k < k0+128; ++k)
        acc += hstate[k][rr]*bf2f(encWb[k*CC + c]);
      encp[tid>>8][rr][c] = acc;
    }
    __syncthreads();
    if (tid < 256) {
      int c = tid & 127, rr = tid>>7;
      ctx[((size_t)t*BB + b0 + rr)*CC + c] = encp[0][rr][c] + encp[1][rr][c] + encb[c];
    }
  }
}

// ---------------- fused SDE scan: MFMA + depth-8 gld_lds slot ring -----------
// 32 blocks x 512 threads (8 waves). Block owns 16 batch rows.
#define AP_SCAT(row,k) (((k)>>5)*512 + ((row) + ((((k)>>3)&3)<<4))*8 + ((k)&7))

// LDS layout (bytes):
#define O_INP  0         // 6144:  bf16 frag-packed z(ks0-1)||ctx(ks2-5)
#define O_A1   6144      // 16384: layer-1 activations (h then f)
#define O_A2   22528     // 16384: layer-2 activations (h then f)
#define O_L3F  38912     // 4096:  f32 [16][64] fz
#define O_L3H  43008     // 4096:  f32 [16][64] hz
#define O_STG  47104     // 65536: weight stage, 8 waves x 8 slots x 1KB
#define SMEM_SZ 112640

// Pipelined weight-stream GEMM phase. Wave-private depth-8 slot ring,
// counted vmcnt (steady state 7 loads in flight), no barriers inside.
template<int KS, int NTW>
__device__ __forceinline__ void mlp_phase(
    const ushort_t* __restrict__ Wb, int strideNt, int ntBase,
    const __bf16* A, ushort_t* slot0, int lane, f32x4* acc)
{
  constexpr int N = KS*NTW;
  constexpr int D = (N < 8) ? N : 8;
  #pragma unroll
  for (int f = 0; f < D; ++f) {
    const int ks = f / NTW, i = f % NTW;
    gld16(Wb + (((size_t)(ks*strideNt + ntBase + i)) << 9) + lane*8,
          slot0 + (f&7)*512);
  }
  bf16x8 a = *(const bf16x8*)(A + lane*8);
  #pragma unroll
  for (int f = 0; f < N; ++f) {
    const int ks = f / NTW, i = f % NTW;
    const int issued = (f + D < N) ? (f + D) : N;
    waitv(issued - f - 1);                       // load f complete
    bf16x8 b = *(const bf16x8*)(slot0 + (f&7)*512 + lane*8);
    if (i == 0 && ks > 0) a = *(const bf16x8*)(A + (ks<<9) + lane*8);
    asm volatile("s_waitcnt lgkmcnt(0)" ::: "memory");  // a,b in regs before slot reuse
    __builtin_amdgcn_sched_barrier(0);
    if (f + D < N) {
      const int f2 = f + D, ks2 = f2 / NTW, i2 = f2 % NTW;
      gld16(Wb + (((size_t)(ks2*strideNt + ntBase + i2)) << 9) + lane*8,
            slot0 + (f2&7)*512);
    }
    acc[(NTW==4) ? i : 0] = MFMA_B16(a, b, acc[(NTW==4) ? i : 0]);
  }
}

__global__ __launch_bounds__(512) void sde_kernel(
  const float* __restrict__ ctx, const float* __restrict__ ts,
  const float* __restrict__ eps0, const float* __restrict__ dW,
  const float* __restrict__ qzW, const float* __restrict__ qzb,
  const float* __restrict__ pm, const float* __restrict__ pls,
  const ushort_t* __restrict__ W1fp, const ushort_t* __restrict__ W1hp,
  const ushort_t* __restrict__ W2fp, const ushort_t* __restrict__ W2hp,
  const ushort_t* __restrict__ W3fp, const ushort_t* __restrict__ W3hp,
  const float* __restrict__ fb1, const float* __restrict__ hb1,
  const float* __restrict__ fb2, const float* __restrict__ hb2,
  const float* __restrict__ fb3, const float* __restrict__ hb3,
  const float* __restrict__ gtab,
  const float* __restrict__ gw1, const float* __restrict__ gb1,
  const float* __restrict__ gw2, const float* __restrict__ gb2,
  const ushort_t* __restrict__ projWp, const float* __restrict__ projb,
  float* __restrict__ out)
{
  __shared__ __align__(16) unsigned char smem[SMEM_SZ];
  __bf16* INp = (__bf16*)(smem + O_INP);
  __bf16* A1  = (__bf16*)(smem + O_A1);
  __bf16* A2  = (__bf16*)(smem + O_A2);
  float*  l3f = (float*)(smem + O_L3F);
  float*  l3h = (float*)(smem + O_L3H);
  ushort_t* stg = (ushort_t*)(smem + O_STG);

  const int tid = threadIdx.x;
  const int b0 = blockIdx.x * 16;
  const int w = tid >> 6, lane = tid & 63;
  ushort_t* myslot = stg + w*4096;   // 8 x 512 ushorts

  // per-thread persistent state: rows w and w+8, column l=lane
  float zA, zB, dlA = 0.f, dlB = 0.f, lqA, lqB, dwA, dwB;

  // ---- z0 phase ----
  {
    float* ctx0f = (float*)A1;   // 8KB scratch
    float* qf    = (float*)A2;   // 8KB scratch
    #pragma unroll
    for (int q = 0; q < 4; ++q) {
      int o = tid + q*512;
      ctx0f[o] = ctx[(size_t)(b0 + (o>>7))*CC + (o&127)];
    }
    __syncthreads();
    #pragma unroll
    for (int q = 0; q < 4; ++q) {
      int o = tid + q*512;
      int r = o >> 7, n = o & 127;
      float acc = qzb[n];
      #pragma unroll 4
      for (int k = 0; k < CC; ++k) acc += ctx0f[r*128 + k]*qzW[k*128 + n];
      qf[o] = acc;
    }
    __syncthreads();
    #pragma unroll
    for (int e = 0; e < 2; ++e) {
      int r = w + e*8, l = lane;
      float qm  = qf[r*128 + l];
      float qls = fminf(fmaxf(qf[r*128 + 64 + l], -20.f), 2.f);
      float z0  = qm + __expf(qls)*eps0[(size_t)(b0+r)*LL + l];
      if (e == 0) zA = z0; else zB = z0;
      INp[AP_SCAT(r, l)] = (__bf16)z0;
      float dp = (z0 - pm[l])*__expf(-pls[l]);
      float dq = (z0 - qm)*__expf(-qls);
      float v = (-0.5f*dp*dp - pls[l]) - (-0.5f*dq*dq - qls);
      #pragma unroll
      for (int off = 1; off < 64; off <<= 1) v += __shfl_xor(v, off);
      if (e == 0) lqA = v; else lqB = v;
    }
    // stage ctx[1] into INp ctx region
    #pragma unroll
    for (int q = 0; q < 4; ++q) {
      int o = tid + q*512;
      int r = o >> 7, c = o & 127;
      INp[AP_SCAT(r, 64 + c)] = (__bf16)ctx[((size_t)1*BB + b0 + r)*CC + c];
    }
    dwA = dW[((size_t)0*BB + b0 + w)*LL + lane];
    dwB = dW[((size_t)0*BB + b0 + w + 8)*LL + lane];
    __syncthreads();
    // proj of z0 via MFMA (waves 0,1)
    if (w < 2) {
      f32x4 pc = {0,0,0,0};
      bf16x8 a0 = *(const bf16x8*)(INp + lane*8);
      bf16x8 b0f = *(const bf16x8*)(projWp + (size_t)(0*2 + w)*512 + lane*8);
      pc = MFMA_B16(a0, b0f, pc);
      bf16x8 a1 = *(const bf16x8*)(INp + 512 + lane*8);
      bf16x8 b1f = *(const bf16x8*)(projWp + (size_t)(1*2 + w)*512 + lane*8);
      pc = MFMA_B16(a1, b1f, pc);
      int col = w*16 + (lane & 15);
      float pb = projb[col];
      #pragma unroll
      for (int j = 0; j < 4; ++j) {
        int row = ((lane>>4)<<2) + j;
        out[((size_t)(b0+row)*TT + 0)*DD + col] = pc[j] + pb;
      }
    }
    __syncthreads();
  }

  // ---- SDE scan ----
  for (int t = 0; t < TT-1; ++t) {
    // P1h: layer1 h-path (K=64) INp -> A1
    {
      f32x4 acc[4] = {{0,0,0,0},{0,0,0,0},{0,0,0,0},{0,0,0,0}};
      mlp_phase<2,4>(W1hp, 32, w*4, INp, myslot, lane, acc);
      #pragma unroll
      for (int i = 0; i < 4; ++i) {
        int c = ((w*4 + i)<<4) + (lane & 15);
        float bv = hb1[c];
        #pragma unroll
        for (int j = 0; j < 4; ++j)
          A1[AP_SCAT(((lane>>4)<<2) + j, c)] = (__bf16)softplus_f(acc[i][j] + bv);
      }
    }
    __syncthreads();
    // P2h: layer2 h-path A1 -> A2
    {
      f32x4 acc[4] = {{0,0,0,0},{0,0,0,0},{0,0,0,0},{0,0,0,0}};
      mlp_phase<16,4>(W2hp, 32, w*4, A1, myslot, lane, acc);
      #pragma unroll
      for (int i = 0; i < 4; ++i) {
        int c = ((w*4 + i)<<4) + (lane & 15);
        float bv = hb2[c];
        #pragma unroll
        for (int j = 0; j < 4; ++j)
          A2[AP_SCAT(((lane>>4)<<2) + j, c)] = (__bf16)softplus_f(acc[i][j] + bv);
      }
    }
    __syncthreads();
    // P3h: layer3 h-path A2 -> l3h (waves 0-3)
    if (w < 4) {
      f32x4 acc[1] = {{0,0,0,0}};
      mlp_phase<16,1>(W3hp, 4, w, A2, myslot, lane, acc);
      int cl = (w<<4) + (lane & 15);
      float bv = hb3[cl];
      #pragma unroll
      for (int j = 0; j < 4; ++j)
        l3h[(((lane>>4)<<2) + j)*64 + cl] = acc[0][j] + bv;
    }
    __syncthreads();
    // P1f: layer1 f-path (K=192) INp -> A1
    {
      f32x4 acc[4] = {{0,0,0,0},{0,0,0,0},{0,0,0,0},{0,0,0,0}};
      mlp_phase<6,4>(W1fp, 32, w*4, INp, myslot, lane, acc);
      #pragma unroll
      for (int i = 0; i < 4; ++i) {
        int c = ((w*4 + i)<<4) + (lane & 15);
        float bv = fb1[c];
        #pragma unroll
        for (int j = 0; j < 4; ++j)
          A1[AP_SCAT(((lane>>4)<<2) + j, c)] = (__bf16)softplus_f(acc[i][j] + bv);
      }
    }
    __syncthreads();
    // P2f: layer2 f-path A1 -> A2
    {
      f32x4 acc[4] = {{0,0,0,0},{0,0,0,0},{0,0,0,0},{0,0,0,0}};
      mlp_phase<16,4>(W2fp, 32, w*4, A1, myslot, lane, acc);
      #pragma unroll
      for (int i = 0; i < 4; ++i) {
        int c = ((w*4 + i)<<4) + (lane & 15);
        float bv = fb2[c];
        #pragma unroll
        for (int j = 0; j < 4; ++j)
          A2[AP_SCAT(((lane>>4)<<2) + j, c)] = (__bf16)softplus_f(acc[i][j] + bv);
      }
    }
    __syncthreads();
    // P3f: layer3 f-path A2 -> l3f (waves 0-3)
    if (w < 4) {
      f32x4 acc[1] = {{0,0,0,0}};
      mlp_phase<16,1>(W3fp, 4, w, A2, myslot, lane, acc);
      int cl = (w<<4) + (lane & 15);
      float bv = fb3[cl];
      #pragma unroll
      for (int j = 0; j < 4; ++j)
        l3f[(((lane>>4)<<2) + j)*64 + cl] = acc[0][j] + bv;
    }
    __syncthreads();

    // ---- epilogue: g via LUT, u, dlog, z update; stage ctx/dW for next ----
    {
      float t0 = ts[t], t1 = ts[t+1];
      float dt = t1 - t0;
      float sqdt = sqrtf(dt);
      float sqA, sqB;
      #pragma unroll
      for (int e = 0; e < 2; ++e) {
        int r = w + e*8, l = lane;
        float zv = e ? zB : zA;
        float gz;
        if (__builtin_expect(fabsf(zv) < 63.9f, 1)) {
          float x = (zv - GZMIN)*GSCALE;
          int jx = (int)x;
          float fr = x - (float)jx;
          const float* gt = &gtab[l*GK + jx];
          float g0v = gt[0], g1v = gt[1];
          gz = g0v + (g1v - g0v)*fr;
        } else {
          float s = 0.f;
          for (int h = 0; h < 512; ++h)
            s += softplus_f(zv*gw1[l*512+h] + gb1[l*512+h]) * gw2[l*512+h];
          gz = sigmoid_f(s + gb2[l]);
        }
        float fzv = l3f[r*64 + l], hzv = l3h[r*64 + l];
        float u = (fzv - hzv)/gz;
        float sq = u*u;
        #pragma unroll
        for (int off = 1; off < 64; off <<= 1) sq += __shfl_xor(sq, off);
        float zn = zv + fzv*dt + gz*sqdt*(e ? dwB : dwA);
        if (e == 0) { sqA = sq; zA = zn; } else { sqB = sq; zB = zn; }
        INp[AP_SCAT(r, l)] = (__bf16)zn;
      }
      dlA += 0.5f*sqA*dt;
      dlB += 0.5f*sqB*dt;
      if (t + 2 < TT) {
        #pragma unroll
        for (int q = 0; q < 4; ++q) {
          int o = tid + q*512;
          int r = o >> 7, c = o & 127;
          INp[AP_SCAT(r, 64 + c)] = (__bf16)ctx[((size_t)(t+2)*BB + b0 + r)*CC + c];
        }
      }
      if (t + 1 < TT-1) {
        dwA = dW[((size_t)(t+1)*BB + b0 + w)*LL + lane];
        dwB = dW[((size_t)(t+1)*BB + b0 + w + 8)*LL + lane];
      }
    }
    __syncthreads();

    // ---- proj of z_{t+1} via MFMA (waves 0,1); other waves fall through ----
    if (w < 2) {
      f32x4 pc = {0,0,0,0};
      bf16x8 a0 = *(const bf16x8*)(INp + lane*8);
      bf16x8 b0f = *(const bf16x8*)(projWp + (size_t)(0*2 + w)*512 + lane*8);
      pc = MFMA_B16(a0, b0f, pc);
      bf16x8 a1 = *(const bf16x8*)(INp + 512 + lane*8);
      bf16x8 b1f = *(const bf16x8*)(projWp + (size_t)(1*2 + w)*512 + lane*8);
      pc = MFMA_B16(a1, b1f, pc);
      int col = w*16 + (lane & 15);
      float pb = projb[col];
      #pragma unroll
      for (int j = 0; j < 4; ++j) {
        int row = ((lane>>4)<<2) + j;
        out[((size_t)(b0+row)*TT + (t+1))*DD + col] = pc[j] + pb;
      }
    }
    // no barrier: next P1h reads INp (stable) and stages into wave-private slots
  }

  if (lane == 0) {
    out[(size_t)BB*TT*DD + b0 + w]     = lqA - dlA;
    out[(size_t)BB*TT*DD + b0 + w + 8] = lqB - dlB;
  }
}

extern "C" void kernel_launch(void* const* d_in, const int* in_sizes, int n_in,
                              void* d_out, int out_size, void* d_ws, size_t ws_size,
                              hipStream_t stream)
{
  const float* xs   = (const float*)d_in[0];
  const float* ts   = (const float*)d_in[1];
  const float* eps0 = (const float*)d_in[2];
  const float* dW   = (const float*)d_in[3];
  const float* gruWx= (const float*)d_in[4];
  const float* gruWh= (const float*)d_in[5];
  const float* grub = (const float*)d_in[6];
  const float* encW = (const float*)d_in[7];
  const float* encb = (const float*)d_in[8];
  const float* qzW  = (const float*)d_in[9];
  const float* qzb  = (const float*)d_in[10];
  const float* fW1  = (const float*)d_in[11];
  const float* fb1  = (const float*)d_in[12];
  const float* fW2  = (const float*)d_in[13];
  const float* fb2  = (const float*)d_in[14];
  const float* fW3  = (const float*)d_in[15];
  const float* fb3  = (const float*)d_in[16];
  const float* hW1  = (const float*)d_in[17];
  const float* hb1  = (const float*)d_in[18];
  const float* hW2  = (const float*)d_in[19];
  const float* hb2  = (const float*)d_in[20];
  const float* hW3  = (const float*)d_in[21];
  const float* hb3  = (const float*)d_in[22];
  const float* gw1  = (const float*)d_in[23];
  const float* gb1  = (const float*)d_in[24];
  const float* gw2  = (const float*)d_in[25];
  const float* gb2  = (const float*)d_in[26];
  const float* projW= (const float*)d_in[27];
  const float* projb= (const float*)d_in[28];
  const float* pm   = (const float*)d_in[29];
  const float* pls  = (const float*)d_in[30];
  float* out = (float*)d_out;
  float* ws  = (float*)d_ws;

  float* ctx  = ws;                              // 16,777,216 f32
  float* gtab = ctx + (size_t)16777216;          // 262,208 f32
  ushort_t* W1fp  = (ushort_t*)(gtab + 262208);  // 98,304
  ushort_t* W1hp  = W1fp + 98304;                // 32,768
  ushort_t* W2fp  = W1hp + 32768;                // 262,144
  ushort_t* W2hp  = W2fp + 262144;               // 262,144
  ushort_t* W3fp  = W2hp + 262144;               // 32,768
  ushort_t* W3hp  = W3fp + 32768;                // 32,768
  ushort_t* encWb = W3hp + 32768;                // 32,768
  uint_t*   Wgru  = (uint_t*)(encWb + 32768);    // 73,984 uints
  ushort_t* Wgn   = (ushort_t*)(Wgru + 73984);   // 73,984
  ushort_t* projWp= Wgn + 73984;                 // 2,048

  hipLaunchKernelGGL(prep_kernel, dim3(3241), dim3(256), 0, stream,
                     fW1, hW1, fW2, hW2, fW3, hW3, gruWx, gruWh, encW, projW,
                     W1fp, W1hp, W2fp, W2hp, W3fp, W3hp, encWb, Wgru, Wgn, projWp);
  hipLaunchKernelGGL(lut_kernel, dim3(1025), dim3(256), 0, stream,
                     gw1, gb1, gw2, gb2, gtab);
  hipLaunchKernelGGL(gru_kernel, dim3(256), dim3(512), 0, stream,
                     xs, ts, Wgru, Wgn, grub, encWb, encb, ctx);
  hipLaunchKernelGGL(sde_kernel, dim3(32), dim3(512), 0, stream,
                     ctx, ts, eps0, dW, qzW, qzb, pm, pls,
                     W1fp, W1hp, W2fp, W2hp, W3fp, W3hp,
                     fb1, hb1, fb2, hb2, fb3, hb3,
                     gtab, gw1, gb1, gw2, gb2, projWp, projb, out);
}

// Round 11
// 9361.187 us; speedup vs baseline: 1.7068x; 1.2441x over previous
//
#include <hip/hip_runtime.h>
#include <math.h>

typedef unsigned int uint_t;
typedef unsigned short ushort_t;
typedef __bf16 bf16x8 __attribute__((ext_vector_type(8)));
typedef float f32x4 __attribute__((ext_vector_type(4)));

#define BB 512
#define TT 256
#define DD 32
#define LL 64
#define CC 128
#define HH 512
#define HE 256
#define LOG2PI_ 1.8378770664093453f
#define GK 4097
#define GSCALE 32.0f
#define GZMIN (-64.0f)

__device__ __forceinline__ float softplus_f(float x) {
  float ax = fabsf(x);
  return fmaxf(x, 0.0f) + __logf(1.0f + __expf(-ax));
}
__device__ __forceinline__ float sigmoid_f(float x) {
  return 1.0f / (1.0f + __expf(-x));
}
__device__ __forceinline__ float bf2f(ushort_t s) {
  return __uint_as_float(((uint_t)s) << 16);
}
__device__ __forceinline__ float bflo(uint_t u) { return __uint_as_float(u << 16); }
__device__ __forceinline__ float bfhi(uint_t u) { return __uint_as_float(u & 0xffff0000u); }
__device__ __forceinline__ ushort_t f2bf(float f) {
  uint_t u = __float_as_uint(f);
  return (ushort_t)((u + 0x7fffu + ((u >> 16) & 1u)) >> 16);
}

#define MFMA_B16(a,b,c) __builtin_amdgcn_mfma_f32_16x16x32_bf16(a,b,c,0,0,0)

// async global->LDS, 16B per lane; LDS base must be wave-uniform.
__device__ __forceinline__ void gld16(const ushort_t* g, ushort_t* l) {
  __builtin_amdgcn_global_load_lds(
      (const __attribute__((address_space(1))) unsigned int*)(const void*)g,
      (__attribute__((address_space(3))) unsigned int*)(void*)l, 16, 0, 0);
}

// ---------------- prep: pack weights into MFMA fragment order -------------
// B-frag (ks,nt): element = W[k = ks*32 + (l>>4)*8 + j][n = nt*16 + (l&15)]
// at frag*512 + l*8 + j  -> one wave reads/stages a frag as one dwordx4/lane.
__global__ void prep_kernel(
    const float* __restrict__ fW1, const float* __restrict__ hW1,
    const float* __restrict__ fW2, const float* __restrict__ hW2,
    const float* __restrict__ fW3, const float* __restrict__ hW3,
    const float* __restrict__ Wx,  const float* __restrict__ Wh,
    const float* __restrict__ encW, const float* __restrict__ projW,
    ushort_t* __restrict__ W1fp, ushort_t* __restrict__ W1hp,
    ushort_t* __restrict__ W2fp, ushort_t* __restrict__ W2hp,
    ushort_t* __restrict__ W3fp, ushort_t* __restrict__ W3hp,
    ushort_t* __restrict__ encWb,
    uint_t* __restrict__ Wgru, ushort_t* __restrict__ Wgn,
    ushort_t* __restrict__ projWp)
{
  int idx = blockIdx.x*256 + threadIdx.x;
  if (idx < 98304) {                       // W1fp: 6 ks x 32 nt
    int f = idx >> 9, e = idx & 511;
    int ks = f >> 5, nt = f & 31, l = e >> 3, j = e & 7;
    int k = ks*32 + ((l>>4)<<3) + j, n = nt*16 + (l & 15);
    W1fp[idx] = f2bf(fW1[k*512 + n]);
  } else if (idx < 131072) {               // W1hp: 2 ks x 32 nt
    int r = idx - 98304;
    int f = r >> 9, e = r & 511;
    int ks = f >> 5, nt = f & 31, l = e >> 3, j = e & 7;
    int k = ks*32 + ((l>>4)<<3) + j, n = nt*16 + (l & 15);
    W1hp[r] = f2bf(hW1[k*512 + n]);
  } else if (idx < 393216) {               // W2fp: 16 ks x 32 nt
    int r = idx - 131072;
    int f = r >> 9, e = r & 511;
    int ks = f >> 5, nt = f & 31, l = e >> 3, j = e & 7;
    int k = ks*32 + ((l>>4)<<3) + j, n = nt*16 + (l & 15);
    W2fp[r] = f2bf(fW2[k*512 + n]);
  } else if (idx < 655360) {               // W2hp
    int r = idx - 393216;
    int f = r >> 9, e = r & 511;
    int ks = f >> 5, nt = f & 31, l = e >> 3, j = e & 7;
    int k = ks*32 + ((l>>4)<<3) + j, n = nt*16 + (l & 15);
    W2hp[r] = f2bf(hW2[k*512 + n]);
  } else if (idx < 688128) {               // W3fp: 16 ks x 4 nt
    int r = idx - 655360;
    int f = r >> 9, e = r & 511;
    int ks = f >> 2, nt = f & 3, l = e >> 3, j = e & 7;
    int k = ks*32 + ((l>>4)<<3) + j, n = nt*16 + (l & 15);
    W3fp[r] = f2bf(fW3[k*64 + n]);
  } else if (idx < 720896) {               // W3hp
    int r = idx - 688128;
    int f = r >> 9, e = r & 511;
    int ks = f >> 2, nt = f & 3, l = e >> 3, j = e & 7;
    int k = ks*32 + ((l>>4)<<3) + j, n = nt*16 + (l & 15);
    W3hp[r] = f2bf(hW3[k*64 + n]);
  } else if (idx < 753664) {               // encWb
    int r = idx - 720896;
    encWb[r] = f2bf(encW[r]);
  } else if (idx < 827648) {               // GRU weights: (k<289, j<256)
    int r = idx - 753664;
    int k = r >> 8, j = r & 255;
    float wr, wu, wn;
    if (k < 33) { wr = Wx[k*768 + j]; wu = Wx[k*768 + 256 + j]; wn = Wx[k*768 + 512 + j]; }
    else { int kk = k - 33; wr = Wh[kk*768 + j]; wu = Wh[kk*768 + 256 + j]; wn = Wh[kk*768 + 512 + j]; }
    Wgru[r] = (uint_t)f2bf(wr) | ((uint_t)f2bf(wu) << 16);
    Wgn[r]  = f2bf(wn);
  } else if (idx < 829696) {               // projWp: 2 ks x 2 nt
    int r = idx - 827648;
    int f = r >> 9, e = r & 511;
    int ks = f >> 1, nt = f & 1, l = e >> 3, j = e & 7;
    int k = ks*32 + ((l>>4)<<3) + j, n = nt*16 + (l & 15);
    projWp[r] = f2bf(projW[k*32 + n]);
  }
}

// ---------------- g-function lookup table -----------------------------------
__global__ void lut_kernel(const float* __restrict__ gw1, const float* __restrict__ gb1,
                           const float* __restrict__ gw2, const float* __restrict__ gb2,
                           float* __restrict__ gtab)
{
  int idx = blockIdx.x*256 + threadIdx.x;
  if (idx >= 64*GK) return;
  int l = idx / GK, i = idx - l*GK;
  float z = GZMIN + (float)i*(1.0f/GSCALE);
  float s = 0.f;
  for (int h = 0; h < 512; ++h)
    s += softplus_f(z*gw1[l*512+h] + gb1[l*512+h]) * gw2[l*512+h];
  gtab[idx] = sigmoid_f(s + gb2[l]);
}

// ---------------- GRU scan + enc projection (round-5, passing) ---------------
__global__ __launch_bounds__(512) void gru_kernel(
    const float* __restrict__ xs, const float* __restrict__ ts,
    const uint_t* __restrict__ Wgru, const ushort_t* __restrict__ Wgn,
    const float* __restrict__ gb,
    const ushort_t* __restrict__ encWb, const float* __restrict__ encb,
    float* __restrict__ ctx)
{
  __shared__ __align__(16) float hstate[HE][2];
  __shared__ __align__(16) float xv[33][2];
  __shared__ __align__(16) float par[2][HE][2][4];
  __shared__ __align__(16) float encp[2][2][CC];
  const int tid = threadIdx.x;
  const int b0 = blockIdx.x*2;
  const int j = tid & 255;
  const int kh = tid >> 8;
  for (int i = tid; i < HE*2; i += 512) ((float*)hstate)[i] = 0.f;
  __syncthreads();
  for (int t = 0; t < TT; ++t) {
    if (tid < 66) {
      int k = tid >> 1, r = tid & 1;
      xv[k][r] = (k < 32) ? xs[((size_t)(b0+r)*TT + t)*DD + k] : ts[t];
    }
    __syncthreads();
    {
      float pr0=0,pr1=0,pu0=0,pu1=0,px0=0,px1=0,ph0=0,ph1=0;
      if (kh == 0) {
        #pragma unroll 3
        for (int k = 0; k < 33; ++k) {
          uint_t ru = Wgru[k*256 + j];
          float wr = bflo(ru), wu = bfhi(ru), wn = bf2f(Wgn[k*256 + j]);
          float2 a = *(const float2*)&xv[k][0];
          pr0 += a.x*wr; pr1 += a.y*wr;
          pu0 += a.x*wu; pu1 += a.y*wu;
          px0 += a.x*wn; px1 += a.y*wn;
        }
        #pragma unroll 8
        for (int k = 33; k < 145; ++k) {
          uint_t ru = Wgru[k*256 + j];
          float wr = bflo(ru), wu = bfhi(ru), wn = bf2f(Wgn[k*256 + j]);
          float2 a = *(const float2*)&hstate[k-33][0];
          pr0 += a.x*wr; pr1 += a.y*wr;
          pu0 += a.x*wu; pu1 += a.y*wu;
          ph0 += a.x*wn; ph1 += a.y*wn;
        }
      } else {
        #pragma unroll 8
        for (int k = 145; k < 289; ++k) {
          uint_t ru = Wgru[k*256 + j];
          float wr = bflo(ru), wu = bfhi(ru), wn = bf2f(Wgn[k*256 + j]);
          float2 a = *(const float2*)&hstate[k-33][0];
          pr0 += a.x*wr; pr1 += a.y*wr;
          pu0 += a.x*wu; pu1 += a.y*wu;
          ph0 += a.x*wn; ph1 += a.y*wn;
        }
      }
      *(float4*)&par[kh][j][0][0] = make_float4(pr0,pu0,px0,ph0);
      *(float4*)&par[kh][j][1][0] = make_float4(pr1,pu1,px1,ph1);
    }
    __syncthreads();
    if (tid < 256) {
      float br = gb[j], bu = gb[256+j], bn = gb[512+j];
      #pragma unroll
      for (int r = 0; r < 2; ++r) {
        float4 p0 = *(const float4*)&par[0][j][r][0];
        float4 p1 = *(const float4*)&par[1][j][r][0];
        float rg = sigmoid_f(p0.x+p1.x+br);
        float ug = sigmoid_f(p0.y+p1.y+bu);
        float ng = tanhf(p0.z+p1.z+bn + rg*(p0.w+p1.w));
        hstate[j][r] = (1.f-ug)*ng + ug*hstate[j][r];
      }
    }
    __syncthreads();
    {
      int c = tid & 127, rr = (tid>>7)&1, k0 = (tid>>8)*128;
      float acc = 0.f;
      #pragma unroll 8
      for (int k = k0; k < k0+128; ++k)
        acc += hstate[k][rr]*bf2f(encWb[k*CC + c]);
      encp[tid>>8][rr][c] = acc;
    }
    __syncthreads();
    if (tid < 256) {
      int c = tid & 127, rr = tid>>7;
      ctx[((size_t)t*BB + b0 + rr)*CC + c] = encp[0][rr][c] + encp[1][rr][c] + encb[c];
    }
  }
}

// ---------------- fused SDE scan: MFMA + depth-8 ring, read-ahead-2 ----------
// 32 blocks x 512 threads (8 waves). Block owns 16 batch rows.
#define AP_SCAT(row,k) (((k)>>5)*512 + ((row) + ((((k)>>3)&3)<<4))*8 + ((k)&7))

// LDS layout (bytes):
#define O_INP  0         // 6144:  bf16 frag-packed z(ks0-1)||ctx(ks2-5)
#define O_A1   6144      // 16384: layer-1 activations (h then f)
#define O_A2   22528     // 16384: layer-2 activations (h then f)
#define O_L3F  38912     // 4096:  f32 [16][64] fz
#define O_L3H  43008     // 4096:  f32 [16][64] hz
#define O_STG  47104     // 73728: weight stage, 8 waves x (8 ring + 1 trash) x 1KB
#define SMEM_SZ 120832

// Weight-stream GEMM phase, NTW=4 (wave covers nt0..nt0+3), stride 32 frags/ks.
// Depth-8 gld ring (vmcnt(5) counted), ds_read 2 fragments ahead (counted lgkm),
// runtime loop in groups of 4. Tail gld's clamp to frag N-1 -> trash slot.
template<int KS>
__device__ __forceinline__ void phase4(
    const ushort_t* __restrict__ Wb, int nt0,
    const __bf16* __restrict__ A, ushort_t* __restrict__ slot, int lane, f32x4* acc)
{
  constexpr int N = KS*4;
  const size_t lo = (size_t)lane*8;
  #define GA4(f_) (Wb + (((size_t)(((((f_)<N?(f_):N-1))>>2)*32 + nt0 + ((((f_)<N?(f_):N-1))&3)))<<9) + lo)
  #define SL(f_)  (slot + (((f_) < N) ? (((f_)&7)*512) : (8*512)))
  #pragma unroll
  for (int d = 0; d < 8; ++d) gld16(GA4(d), slot + d*512);
  bf16x8 a  = *(const bf16x8*)(A + lo);
  bf16x8 an = a;
  asm volatile("s_waitcnt vmcnt(7)":::"memory");
  bf16x8 p0 = *(const bf16x8*)(slot + 0*512 + lo);
  asm volatile("s_waitcnt vmcnt(6)":::"memory");
  bf16x8 p1 = *(const bf16x8*)(slot + 1*512 + lo);
  bf16x8 p2, p3;
  for (int f0 = 0; f0 < N; f0 += 4) {
    int ks = f0 >> 2;
    asm volatile("s_waitcnt vmcnt(5)":::"memory");          // load f0+2 done
    p2 = *(const bf16x8*)(slot + ((f0+2)&7)*512 + lo);
    asm volatile("s_waitcnt lgkmcnt(2)":::"memory");        // read(f0) drained
    gld16(GA4(f0+8), SL(f0+8));
    acc[0] = MFMA_B16(a, p0, acc[0]);
    asm volatile("s_waitcnt vmcnt(5)":::"memory");          // load f0+3 done
    p3 = *(const bf16x8*)(slot + ((f0+3)&7)*512 + lo);
    asm volatile("s_waitcnt lgkmcnt(2)":::"memory");        // read(f0+1) drained
    gld16(GA4(f0+9), SL(f0+9));
    acc[1] = MFMA_B16(a, p1, acc[1]);
    asm volatile("s_waitcnt vmcnt(5)":::"memory");          // load f0+4 done
    p0 = *(const bf16x8*)(slot + ((f0+4)&7)*512 + lo);
    if (ks + 1 < KS) an = *(const bf16x8*)(A + ((size_t)(ks+1)<<9) + lo);
    asm volatile("s_waitcnt lgkmcnt(3)":::"memory");        // read(f0+2) drained
    gld16(GA4(f0+10), SL(f0+10));
    acc[2] = MFMA_B16(a, p2, acc[2]);
    asm volatile("s_waitcnt vmcnt(5)":::"memory");          // load f0+5 done
    p1 = *(const bf16x8*)(slot + ((f0+5)&7)*512 + lo);
    asm volatile("s_waitcnt lgkmcnt(3)":::"memory");        // read(f0+3) drained
    gld16(GA4(f0+11), SL(f0+11));
    acc[3] = MFMA_B16(a, p3, acc[3]);
    a = an;
  }
  #undef GA4
  #undef SL
}

// NTW=1 (one nt per wave), per-frag A (q) read, stride NTS frags/ks.
template<int KS, int NTS>
__device__ __forceinline__ void phase1(
    const ushort_t* __restrict__ Wb, int nt,
    const __bf16* __restrict__ A, ushort_t* __restrict__ slot, int lane, f32x4& acc)
{
  constexpr int N = KS;
  const size_t lo = (size_t)lane*8;
  #define GA1(f_) (Wb + (((size_t)((((f_)<N?(f_):N-1))*NTS + nt))<<9) + lo)
  #define SL(f_)  (slot + (((f_) < N) ? (((f_)&7)*512) : (8*512)))
  #define QA(f_)  (*(const bf16x8*)(A + ((size_t)(((f_)<N?(f_):N-1))<<9) + lo))
  #pragma unroll
  for (int d = 0; d < 8; ++d) gld16(GA1(d), slot + d*512);
  bf16x8 q0 = QA(0);
  asm volatile("s_waitcnt vmcnt(7)":::"memory");
  bf16x8 p0 = *(const bf16x8*)(slot + 0*512 + lo);
  bf16x8 q1 = QA(1);
  asm volatile("s_waitcnt vmcnt(6)":::"memory");
  bf16x8 p1 = *(const bf16x8*)(slot + 1*512 + lo);
  bf16x8 p2, p3, q2, q3;
  for (int f0 = 0; f0 < N; f0 += 4) {
    q2 = QA(f0+2);
    asm volatile("s_waitcnt vmcnt(5)":::"memory");
    p2 = *(const bf16x8*)(slot + ((f0+2)&7)*512 + lo);
    asm volatile("s_waitcnt lgkmcnt(4)":::"memory");
    gld16(GA1(f0+8), SL(f0+8));
    acc = MFMA_B16(q0, p0, acc);
    q3 = QA(f0+3);
    asm volatile("s_waitcnt vmcnt(5)":::"memory");
    p3 = *(const bf16x8*)(slot + ((f0+3)&7)*512 + lo);
    asm volatile("s_waitcnt lgkmcnt(4)":::"memory");
    gld16(GA1(f0+9), SL(f0+9));
    acc = MFMA_B16(q1, p1, acc);
    q0 = QA(f0+4);
    asm volatile("s_waitcnt vmcnt(5)":::"memory");
    p0 = *(const bf16x8*)(slot + ((f0+4)&7)*512 + lo);
    asm volatile("s_waitcnt lgkmcnt(4)":::"memory");
    gld16(GA1(f0+10), SL(f0+10));
    acc = MFMA_B16(q2, p2, acc);
    q1 = QA(f0+5);
    asm volatile("s_waitcnt vmcnt(5)":::"memory");
    p1 = *(const bf16x8*)(slot + ((f0+5)&7)*512 + lo);
    asm volatile("s_waitcnt lgkmcnt(4)":::"memory");
    gld16(GA1(f0+11), SL(f0+11));
    acc = MFMA_B16(q3, p3, acc);
  }
  #undef GA1
  #undef SL
  #undef QA
}

__global__ __launch_bounds__(512) void sde_kernel(
  const float* __restrict__ ctx, const float* __restrict__ ts,
  const float* __restrict__ eps0, const float* __restrict__ dW,
  const float* __restrict__ qzW, const float* __restrict__ qzb,
  const float* __restrict__ pm, const float* __restrict__ pls,
  const ushort_t* __restrict__ W1fp, const ushort_t* __restrict__ W1hp,
  const ushort_t* __restrict__ W2fp, const ushort_t* __restrict__ W2hp,
  const ushort_t* __restrict__ W3fp, const ushort_t* __restrict__ W3hp,
  const float* __restrict__ fb1, const float* __restrict__ hb1,
  const float* __restrict__ fb2, const float* __restrict__ hb2,
  const float* __restrict__ fb3, const float* __restrict__ hb3,
  const float* __restrict__ gtab,
  const float* __restrict__ gw1, const float* __restrict__ gb1,
  const float* __restrict__ gw2, const float* __restrict__ gb2,
  const ushort_t* __restrict__ projWp, const float* __restrict__ projb,
  float* __restrict__ out)
{
  __shared__ __align__(16) unsigned char smem[SMEM_SZ];
  __bf16* INp = (__bf16*)(smem + O_INP);
  __bf16* A1  = (__bf16*)(smem + O_A1);
  __bf16* A2  = (__bf16*)(smem + O_A2);
  float*  l3f = (float*)(smem + O_L3F);
  float*  l3h = (float*)(smem + O_L3H);
  ushort_t* stg = (ushort_t*)(smem + O_STG);

  const int tid = threadIdx.x;
  const int b0 = blockIdx.x * 16;
  const int w = tid >> 6, lane = tid & 63;
  ushort_t* myslot = stg + w*4608;   // 9 x 512 ushorts (8 ring + trash)

  // per-thread persistent state: rows w and w+8, column l=lane
  float zA, zB, dlA = 0.f, dlB = 0.f, lqA, lqB, dwA, dwB;

  // ---- z0 phase ----
  {
    float* ctx0f = (float*)A1;   // 8KB scratch
    float* qf    = (float*)A2;   // 8KB scratch
    #pragma unroll
    for (int q = 0; q < 4; ++q) {
      int o = tid + q*512;
      ctx0f[o] = ctx[(size_t)(b0 + (o>>7))*CC + (o&127)];
    }
    __syncthreads();
    #pragma unroll
    for (int q = 0; q < 4; ++q) {
      int o = tid + q*512;
      int r = o >> 7, n = o & 127;
      float acc = qzb[n];
      #pragma unroll 4
      for (int k = 0; k < CC; ++k) acc += ctx0f[r*128 + k]*qzW[k*128 + n];
      qf[o] = acc;
    }
    __syncthreads();
    #pragma unroll
    for (int e = 0; e < 2; ++e) {
      int r = w + e*8, l = lane;
      float qm  = qf[r*128 + l];
      float qls = fminf(fmaxf(qf[r*128 + 64 + l], -20.f), 2.f);
      float z0  = qm + __expf(qls)*eps0[(size_t)(b0+r)*LL + l];
      if (e == 0) zA = z0; else zB = z0;
      INp[AP_SCAT(r, l)] = (__bf16)z0;
      float dp = (z0 - pm[l])*__expf(-pls[l]);
      float dq = (z0 - qm)*__expf(-qls);
      float v = (-0.5f*dp*dp - pls[l]) - (-0.5f*dq*dq - qls);
      #pragma unroll
      for (int off = 1; off < 64; off <<= 1) v += __shfl_xor(v, off);
      if (e == 0) lqA = v; else lqB = v;
    }
    // stage ctx[1] into INp ctx region
    #pragma unroll
    for (int q = 0; q < 4; ++q) {
      int o = tid + q*512;
      int r = o >> 7, c = o & 127;
      INp[AP_SCAT(r, 64 + c)] = (__bf16)ctx[((size_t)1*BB + b0 + r)*CC + c];
    }
    dwA = dW[((size_t)0*BB + b0 + w)*LL + lane];
    dwB = dW[((size_t)0*BB + b0 + w + 8)*LL + lane];
    __syncthreads();
    // proj of z0 via MFMA (waves 0,1)
    if (w < 2) {
      f32x4 pc = {0,0,0,0};
      bf16x8 a0 = *(const bf16x8*)(INp + lane*8);
      bf16x8 b0f = *(const bf16x8*)(projWp + (size_t)(0*2 + w)*512 + lane*8);
      pc = MFMA_B16(a0, b0f, pc);
      bf16x8 a1 = *(const bf16x8*)(INp + 512 + lane*8);
      bf16x8 b1f = *(const bf16x8*)(projWp + (size_t)(1*2 + w)*512 + lane*8);
      pc = MFMA_B16(a1, b1f, pc);
      int col = w*16 + (lane & 15);
      float pb = projb[col];
      #pragma unroll
      for (int j = 0; j < 4; ++j) {
        int row = ((lane>>4)<<2) + j;
        out[((size_t)(b0+row)*TT + 0)*DD + col] = pc[j] + pb;
      }
    }
    __syncthreads();
  }

  // ---- SDE scan ----
  for (int t = 0; t < TT-1; ++t) {
    // P1h: layer1 h-path (K=64) INp -> A1
    {
      f32x4 acc[4] = {{0,0,0,0},{0,0,0,0},{0,0,0,0},{0,0,0,0}};
      phase4<2>(W1hp, w*4, INp, myslot, lane, acc);
      #pragma unroll
      for (int i = 0; i < 4; ++i) {
        int c = ((w*4 + i)<<4) + (lane & 15);
        float bv = hb1[c];
        #pragma unroll
        for (int j = 0; j < 4; ++j)
          A1[AP_SCAT(((lane>>4)<<2) + j, c)] = (__bf16)softplus_f(acc[i][j] + bv);
      }
    }
    __syncthreads();
    // P2h: layer2 h-path A1 -> A2
    {
      f32x4 acc[4] = {{0,0,0,0},{0,0,0,0},{0,0,0,0},{0,0,0,0}};
      phase4<16>(W2hp, w*4, A1, myslot, lane, acc);
      #pragma unroll
      for (int i = 0; i < 4; ++i) {
        int c = ((w*4 + i)<<4) + (lane & 15);
        float bv = hb2[c];
        #pragma unroll
        for (int j = 0; j < 4; ++j)
          A2[AP_SCAT(((lane>>4)<<2) + j, c)] = (__bf16)softplus_f(acc[i][j] + bv);
      }
    }
    __syncthreads();
    // P3h: layer3 h-path A2 -> l3h (waves 0-3)
    if (w < 4) {
      f32x4 acc = {0,0,0,0};
      phase1<16,4>(W3hp, w, A2, myslot, lane, acc);
      int cl = (w<<4) + (lane & 15);
      float bv = hb3[cl];
      #pragma unroll
      for (int j = 0; j < 4; ++j)
        l3h[(((lane>>4)<<2) + j)*64 + cl] = acc[j] + bv;
    }
    __syncthreads();
    // P1f: layer1 f-path (K=192) INp -> A1
    {
      f32x4 acc[4] = {{0,0,0,0},{0,0,0,0},{0,0,0,0},{0,0,0,0}};
      phase4<6>(W1fp, w*4, INp, myslot, lane, acc);
      #pragma unroll
      for (int i = 0; i < 4; ++i) {
        int c = ((w*4 + i)<<4) + (lane & 15);
        float bv = fb1[c];
        #pragma unroll
        for (int j = 0; j < 4; ++j)
          A1[AP_SCAT(((lane>>4)<<2) + j, c)] = (__bf16)softplus_f(acc[i][j] + bv);
      }
    }
    __syncthreads();
    // P2f: layer2 f-path A1 -> A2
    {
      f32x4 acc[4] = {{0,0,0,0},{0,0,0,0},{0,0,0,0},{0,0,0,0}};
      phase4<16>(W2fp, w*4, A1, myslot, lane, acc);
      #pragma unroll
      for (int i = 0; i < 4; ++i) {
        int c = ((w*4 + i)<<4) + (lane & 15);
        float bv = fb2[c];
        #pragma unroll
        for (int j = 0; j < 4; ++j)
          A2[AP_SCAT(((lane>>4)<<2) + j, c)] = (__bf16)softplus_f(acc[i][j] + bv);
      }
    }
    __syncthreads();
    // P3f: layer3 f-path A2 -> l3f (waves 0-3)
    if (w < 4) {
      f32x4 acc = {0,0,0,0};
      phase1<16,4>(W3fp, w, A2, myslot, lane, acc);
      int cl = (w<<4) + (lane & 15);
      float bv = fb3[cl];
      #pragma unroll
      for (int j = 0; j < 4; ++j)
        l3f[(((lane>>4)<<2) + j)*64 + cl] = acc[j] + bv;
    }
    __syncthreads();

    // ---- epilogue: g via LUT, u, dlog, z update; stage ctx/dW for next ----
    {
      float t0 = ts[t], t1 = ts[t+1];
      float dt = t1 - t0;
      float sqdt = sqrtf(dt);
      float sqA, sqB;
      #pragma unroll
      for (int e = 0; e < 2; ++e) {
        int r = w + e*8, l = lane;
        float zv = e ? zB : zA;
        float gz;
        if (__builtin_expect(fabsf(zv) < 63.9f, 1)) {
          float x = (zv - GZMIN)*GSCALE;
          int jx = (int)x;
          float fr = x - (float)jx;
          const float* gt = &gtab[l*GK + jx];
          float g0v = gt[0], g1v = gt[1];
          gz = g0v + (g1v - g0v)*fr;
        } else {
          float s = 0.f;
          for (int h = 0; h < 512; ++h)
            s += softplus_f(zv*gw1[l*512+h] + gb1[l*512+h]) * gw2[l*512+h];
          gz = sigmoid_f(s + gb2[l]);
        }
        float fzv = l3f[r*64 + l], hzv = l3h[r*64 + l];
        float u = (fzv - hzv)/gz;
        float sq = u*u;
        #pragma unroll
        for (int off = 1; off < 64; off <<= 1) sq += __shfl_xor(sq, off);
        float zn = zv + fzv*dt + gz*sqdt*(e ? dwB : dwA);
        if (e == 0) { sqA = sq; zA = zn; } else { sqB = sq; zB = zn; }
        INp[AP_SCAT(r, l)] = (__bf16)zn;
      }
      dlA += 0.5f*sqA*dt;
      dlB += 0.5f*sqB*dt;
      if (t + 2 < TT) {
        #pragma unroll
        for (int q = 0; q < 4; ++q) {
          int o = tid + q*512;
          int r = o >> 7, c = o & 127;
          INp[AP_SCAT(r, 64 + c)] = (__bf16)ctx[((size_t)(t+2)*BB + b0 + r)*CC + c];
        }
      }
      if (t + 1 < TT-1) {
        dwA = dW[((size_t)(t+1)*BB + b0 + w)*LL + lane];
        dwB = dW[((size_t)(t+1)*BB + b0 + w + 8)*LL + lane];
      }
    }
    __syncthreads();

    // ---- proj of z_{t+1} via MFMA (waves 0,1); other waves fall through ----
    if (w < 2) {
      f32x4 pc = {0,0,0,0};
      bf16x8 a0 = *(const bf16x8*)(INp + lane*8);
      bf16x8 b0f = *(const bf16x8*)(projWp + (size_t)(0*2 + w)*512 + lane*8);
      pc = MFMA_B16(a0, b0f, pc);
      bf16x8 a1 = *(const bf16x8*)(INp + 512 + lane*8);
      bf16x8 b1f = *(const bf16x8*)(projWp + (size_t)(1*2 + w)*512 + lane*8);
      pc = MFMA_B16(a1, b1f, pc);
      int col = w*16 + (lane & 15);
      float pb = projb[col];
      #pragma unroll
      for (int j = 0; j < 4; ++j) {
        int row = ((lane>>4)<<2) + j;
        out[((size_t)(b0+row)*TT + (t+1))*DD + col] = pc[j] + pb;
      }
    }
    // no barrier: next P1h reads INp (stable) and stages into wave-private slots
  }

  if (lane == 0) {
    out[(size_t)BB*TT*DD + b0 + w]     = lqA - dlA;
    out[(size_t)BB*TT*DD + b0 + w + 8] = lqB - dlB;
  }
}

extern "C" void kernel_launch(void* const* d_in, const int* in_sizes, int n_in,
                              void* d_out, int out_size, void* d_ws, size_t ws_size,
                              hipStream_t stream)
{
  const float* xs   = (const float*)d_in[0];
  const float* ts   = (const float*)d_in[1];
  const float* eps0 = (const float*)d_in[2];
  const float* dW   = (const float*)d_in[3];
  const float* gruWx= (const float*)d_in[4];
  const float* gruWh= (const float*)d_in[5];
  const float* grub = (const float*)d_in[6];
  const float* encW = (const float*)d_in[7];
  const float* encb = (const float*)d_in[8];
  const float* qzW  = (const float*)d_in[9];
  const float* qzb  = (const float*)d_in[10];
  const float* fW1  = (const float*)d_in[11];
  const float* fb1  = (const float*)d_in[12];
  const float* fW2  = (const float*)d_in[13];
  const float* fb2  = (const float*)d_in[14];
  const float* fW3  = (const float*)d_in[15];
  const float* fb3  = (const float*)d_in[16];
  const float* hW1  = (const float*)d_in[17];
  const float* hb1  = (const float*)d_in[18];
  const float* hW2  = (const float*)d_in[19];
  const float* hb2  = (const float*)d_in[20];
  const float* hW3  = (const float*)d_in[21];
  const float* hb3  = (const float*)d_in[22];
  const float* gw1  = (const float*)d_in[23];
  const float* gb1  = (const float*)d_in[24];
  const float* gw2  = (const float*)d_in[25];
  const float* gb2  = (const float*)d_in[26];
  const float* projW= (const float*)d_in[27];
  const float* projb= (const float*)d_in[28];
  const float* pm   = (const float*)d_in[29];
  const float* pls  = (const float*)d_in[30];
  float* out = (float*)d_out;
  float* ws  = (float*)d_ws;

  float* ctx  = ws;                              // 16,777,216 f32
  float* gtab = ctx + (size_t)16777216;          // 262,208 f32
  ushort_t* W1fp  = (ushort_t*)(gtab + 262208);  // 98,304
  ushort_t* W1hp  = W1fp + 98304;                // 32,768
  ushort_t* W2fp  = W1hp + 32768;                // 262,144
  ushort_t* W2hp  = W2fp + 262144;               // 262,144
  ushort_t* W3fp  = W2hp + 262144;               // 32,768
  ushort_t* W3hp  = W3fp + 32768;                // 32,768
  ushort_t* encWb = W3hp + 32768;                // 32,768
  uint_t*   Wgru  = (uint_t*)(encWb + 32768);    // 73,984 uints
  ushort_t* Wgn   = (ushort_t*)(Wgru + 73984);   // 73,984
  ushort_t* projWp= Wgn + 73984;                 // 2,048

  hipLaunchKernelGGL(prep_kernel, dim3(3241), dim3(256), 0, stream,
                     fW1, hW1, fW2, hW2, fW3, hW3, gruWx, gruWh, encW, projW,
                     W1fp, W1hp, W2fp, W2hp, W3fp, W3hp, encWb, Wgru, Wgn, projWp);
  hipLaunchKernelGGL(lut_kernel, dim3(1025), dim3(256), 0, stream,
                     gw1, gb1, gw2, gb2, gtab);
  hipLaunchKernelGGL(gru_kernel, dim3(256), dim3(512), 0, stream,
                     xs, ts, Wgru, Wgn, grub, encWb, encb, ctx);
  hipLaunchKernelGGL(sde_kernel, dim3(32), dim3(512), 0, stream,
                     ctx, ts, eps0, dW, qzW, qzb, pm, pls,
                     W1fp, W1hp, W2fp, W2hp, W3fp, W3hp,
                     fb1, hb1, fb2, hb2, fb3, hb3,
                     gtab, gw1, gb1, gw2, gb2, projWp, projb, out);
}